// Round 1
// baseline (413.174 us; speedup 1.0000x reference)
//
#include <hip/hip_runtime.h>

#define NN 8000
#define NE 64000
#define INF 16
#define HH 128
#define MM 16
#define EDF 4
#define OUTF 4
#define NL 2
#define BN_EPS 1e-5f

__global__ void deg_count_k(const int* __restrict__ ei, float* __restrict__ deg) {
  int e = blockIdx.x * blockDim.x + threadIdx.x;
  if (e < NE) atomicAdd(&deg[ei[NE + e]], 1.0f);
}

__global__ void in_proj_k(const float* __restrict__ x, const float* __restrict__ W,
                          const float* __restrict__ b, float* __restrict__ h) {
  int n = blockIdx.x;
  int t = threadIdx.x;  // 0..127
  __shared__ float sx[INF];
  if (t < INF) sx[t] = x[n * INF + t];
  __syncthreads();
  float acc = b[t];
#pragma unroll
  for (int i = 0; i < INF; ++i) acc = fmaf(sx[i], W[i * HH + t], acc);
  h[n * HH + t] = acc;
}

// W2T[h*2048 + k*16 + m] = W2[k*2048 + h*16 + m]
__global__ void w2t_k(const float* __restrict__ W2, float* __restrict__ W2T) {
  int idx = blockIdx.x * 256 + threadIdx.x;
  if (idx >= HH * HH * MM) return;
  int h = idx >> 11;
  int r = idx & 2047;
  int k = r >> 4, m = r & 15;
  W2T[idx] = W2[k * (HH * MM) + h * MM + m];
}

// C[8000 x 2048] = A[8000 x 128] @ B[128 x 2048]
__global__ __launch_bounds__(256) void gemm_qn_k(const float* __restrict__ A,
                                                 const float* __restrict__ B,
                                                 float* __restrict__ C) {
  __shared__ float As[16][65];
  __shared__ float Bs[16][65];
  int br = blockIdx.y * 64;
  int bc = blockIdx.x * 64;
  int tid = threadIdx.x;
  int tr = (tid >> 4) << 2;
  int tc = (tid & 15) << 2;
  float acc[4][4] = {};
  for (int k0 = 0; k0 < HH; k0 += 16) {
#pragma unroll
    for (int i = tid; i < 64 * 16; i += 256) {
      int r = i >> 4, kk = i & 15;
      As[kk][r] = A[(br + r) * HH + k0 + kk];
    }
#pragma unroll
    for (int i = tid; i < 16 * 64; i += 256) {
      int kk = i >> 6, c = i & 63;
      Bs[kk][c] = B[(k0 + kk) * (HH * MM) + bc + c];
    }
    __syncthreads();
#pragma unroll
    for (int kk = 0; kk < 16; ++kk) {
      float a[4], bb[4];
#pragma unroll
      for (int xx = 0; xx < 4; ++xx) a[xx] = As[kk][tr + xx];
#pragma unroll
      for (int yy = 0; yy < 4; ++yy) bb[yy] = Bs[kk][tc + yy];
#pragma unroll
      for (int xx = 0; xx < 4; ++xx)
#pragma unroll
        for (int yy = 0; yy < 4; ++yy) acc[xx][yy] = fmaf(a[xx], bb[yy], acc[xx][yy]);
    }
    __syncthreads();
  }
#pragma unroll
  for (int xx = 0; xx < 4; ++xx) {
    int r = br + tr + xx;
#pragma unroll
    for (int yy = 0; yy < 4; ++yy) C[r * (HH * MM) + bc + tc + yy] = acc[xx][yy];
  }
}

// B2[n,m] = sum_h h[n,h] * b2[h*16+m]
__global__ void b2_term_k(const float* __restrict__ h, const float* __restrict__ b2,
                          float* __restrict__ B2) {
  __shared__ float sb2[HH * MM];
  for (int i = threadIdx.x; i < HH * MM; i += 256) sb2[i] = b2[i];
  __syncthreads();
  int t = threadIdx.x;
  int n = blockIdx.x * 16 + (t >> 4);
  int m = t & 15;
  const float* hr = h + n * HH;
  float s = 0.f;
#pragma unroll
  for (int k = 0; k < HH; ++k) s = fmaf(hr[k], sb2[k * MM + m], s);
  B2[n * MM + m] = s;
}

// one wave per edge: msgs[e,m] = sum_k relu1[e,k]*Qn[src,k,m]; atomic into agg[dst]
__global__ __launch_bounds__(256) void edge_msg_k(const int* __restrict__ ei,
                                                  const float* __restrict__ ea,
                                                  const float* __restrict__ W1,
                                                  const float* __restrict__ b1,
                                                  const float* __restrict__ Qn,
                                                  const float* __restrict__ B2,
                                                  float* __restrict__ agg) {
  __shared__ float sW1[EDF * HH];
  __shared__ float sb1[HH];
  int tid = threadIdx.x;
  for (int i = tid; i < EDF * HH; i += 256) sW1[i] = W1[i];
  if (tid < HH) sb1[tid] = b1[tid];
  __syncthreads();
  int e = blockIdx.x * 4 + (tid >> 6);
  int lane = tid & 63;
  if (e >= NE) return;
  int src = ei[e], dst = ei[NE + e];
  float a0 = ea[e * 4 + 0], a1 = ea[e * 4 + 1], a2 = ea[e * 4 + 2], a3 = ea[e * 4 + 3];
  int kg = lane >> 4;
  const float* q = Qn + (size_t)src * (HH * MM);
  float acc = 0.f;
#pragma unroll
  for (int j = 0; j < 32; ++j) {
    int k = (j << 2) + kg;
    float r = fmaf(a3, sW1[3 * HH + k],
               fmaf(a2, sW1[2 * HH + k], fmaf(a1, sW1[HH + k], fmaf(a0, sW1[k], sb1[k]))));
    r = fmaxf(r, 0.f);
    acc = fmaf(r, q[(j << 6) + lane], acc);
  }
  acc += __shfl_xor(acc, 16);
  acc += __shfl_xor(acc, 32);
  if (lane < 16) atomicAdd(&agg[dst * MM + lane], acc + B2[src * MM + lane]);
}

// x_msg = agg/deg + h@rootW + cbias ; h_pre = h + x_msg@msgW + msgb
__global__ void node_update_k(const float* __restrict__ h, const float* __restrict__ agg,
                              const float* __restrict__ deg, const float* __restrict__ rootW,
                              const float* __restrict__ cbias, const float* __restrict__ msgW,
                              const float* __restrict__ msgb, float* __restrict__ h_pre) {
  int n = blockIdx.x;
  int t = threadIdx.x;  // 0..127
  __shared__ float sh[HH];
  __shared__ float xm[MM];
  sh[t] = h[n * HH + t];
  __syncthreads();
  if (t < MM) {
    float s = 0.f;
#pragma unroll
    for (int k = 0; k < HH; ++k) s = fmaf(sh[k], rootW[k * MM + t], s);
    xm[t] = agg[n * MM + t] / fmaxf(deg[n], 1.0f) + s + cbias[t];
  }
  __syncthreads();
  float hp = sh[t] + msgb[t];
#pragma unroll
  for (int m = 0; m < MM; ++m) hp = fmaf(xm[m], msgW[m * HH + t], hp);
  h_pre[n * HH + t] = hp;
}

__global__ void bn_partial_k(const float* __restrict__ hp, float* __restrict__ sums) {
  int c = threadIdx.x;  // 0..127
  int n0 = blockIdx.x * 32;
  float s = 0.f, ss = 0.f;
  for (int i = 0; i < 32; ++i) {
    float v = hp[(n0 + i) * HH + c];
    s += v;
    ss = fmaf(v, v, ss);
  }
  atomicAdd(&sums[c], s);
  atomicAdd(&sums[HH + c], ss);
}

__global__ void bn_final_k(const float* __restrict__ sums, const float* __restrict__ gamma,
                           const float* __restrict__ beta, float* __restrict__ sc) {
  int c = threadIdx.x;
  float mu = sums[c] * (1.0f / NN);
  float var = sums[HH + c] * (1.0f / NN) - mu * mu;
  float s = gamma[c] * rsqrtf(var + BN_EPS);
  sc[c] = s;
  sc[HH + c] = beta[c] - mu * s;
}

__global__ void norm_relu_k(const float* __restrict__ hp, const float* __restrict__ sc,
                            float* __restrict__ h) {
  int i = blockIdx.x * 256 + threadIdx.x;
  if (i >= NN * HH) return;
  int c = i & (HH - 1);
  h[i] = fmaxf(0.f, fmaf(hp[i], sc[c], sc[HH + c]));
}

__global__ void out_proj_k(const float* __restrict__ h, const float* __restrict__ W,
                           const float* __restrict__ b, float* __restrict__ out) {
  int n = blockIdx.x * 4 + (threadIdx.x >> 6);
  int lane = threadIdx.x & 63;
  if (n >= NN) return;
  float acc0 = 0.f, acc1 = 0.f, acc2 = 0.f, acc3 = 0.f;
#pragma unroll
  for (int rep = 0; rep < 2; ++rep) {
    int hh = lane + rep * 64;
    float hv = h[n * HH + hh];
    acc0 = fmaf(hv, W[hh * OUTF + 0], acc0);
    acc1 = fmaf(hv, W[hh * OUTF + 1], acc1);
    acc2 = fmaf(hv, W[hh * OUTF + 2], acc2);
    acc3 = fmaf(hv, W[hh * OUTF + 3], acc3);
  }
#pragma unroll
  for (int s = 32; s > 0; s >>= 1) {
    acc0 += __shfl_down(acc0, s);
    acc1 += __shfl_down(acc1, s);
    acc2 += __shfl_down(acc2, s);
    acc3 += __shfl_down(acc3, s);
  }
  if (lane == 0) {
    out[n * OUTF + 0] = acc0 + b[0];
    out[n * OUTF + 1] = acc1 + b[1];
    out[n * OUTF + 2] = acc2 + b[2];
    out[n * OUTF + 3] = acc3 + b[3];
  }
}

extern "C" void kernel_launch(void* const* d_in, const int* in_sizes, int n_in,
                              void* d_out, int out_size, void* d_ws, size_t ws_size,
                              hipStream_t stream) {
  (void)in_sizes; (void)n_in; (void)out_size; (void)ws_size;
  const float* x    = (const float*)d_in[0];
  const int* ei     = (const int*)d_in[1];
  const float* ea   = (const float*)d_in[2];
  const float* inW  = (const float*)d_in[3];
  const float* inb  = (const float*)d_in[4];
  const float* cW1  = (const float*)d_in[5];
  const float* cb1  = (const float*)d_in[6];
  const float* cW2  = (const float*)d_in[7];
  const float* cb2  = (const float*)d_in[8];
  const float* rW   = (const float*)d_in[9];
  const float* cbias= (const float*)d_in[10];
  const float* gam  = (const float*)d_in[11];
  const float* bet  = (const float*)d_in[12];
  const float* mW   = (const float*)d_in[13];
  const float* mb   = (const float*)d_in[14];
  const float* oW   = (const float*)d_in[15];
  const float* ob   = (const float*)d_in[16];
  float* out = (float*)d_out;

  float* ws = (float*)d_ws;
  size_t off = 0;
  float* deg  = ws + off; off += 8192;
  float* h    = ws + off; off += (size_t)NN * HH;
  float* hpre = ws + off; off += (size_t)NN * HH;
  float* agg  = ws + off; off += (size_t)NN * MM;
  float* B2   = ws + off; off += (size_t)NN * MM;
  float* w2t  = ws + off; off += (size_t)HH * HH * MM;
  float* sums = ws + off; off += 256;
  float* sc   = ws + off; off += 256;
  float* Qn   = ws + off; off += (size_t)NN * HH * MM;

  hipMemsetAsync(deg, 0, NN * sizeof(float), stream);
  deg_count_k<<<(NE + 255) / 256, 256, 0, stream>>>(ei, deg);
  in_proj_k<<<NN, HH, 0, stream>>>(x, inW, inb, h);

  for (int l = 0; l < NL; ++l) {
    w2t_k<<<(HH * HH * MM + 255) / 256, 256, 0, stream>>>(cW2 + (size_t)l * HH * HH * MM, w2t);
    dim3 gg(HH * MM / 64, NN / 64);
    gemm_qn_k<<<gg, 256, 0, stream>>>(h, w2t, Qn);
    b2_term_k<<<NN / 16, 256, 0, stream>>>(h, cb2 + (size_t)l * HH * MM, B2);
    hipMemsetAsync(agg, 0, (size_t)NN * MM * sizeof(float), stream);
    edge_msg_k<<<NE / 4, 256, 0, stream>>>(ei, ea, cW1 + (size_t)l * EDF * HH,
                                           cb1 + (size_t)l * HH, Qn, B2, agg);
    node_update_k<<<NN, HH, 0, stream>>>(h, agg, deg, rW + (size_t)l * HH * MM,
                                         cbias + (size_t)l * MM, mW + (size_t)l * MM * HH,
                                         mb + (size_t)l * HH, hpre);
    hipMemsetAsync(sums, 0, 2 * HH * sizeof(float), stream);
    bn_partial_k<<<NN / 32, HH, 0, stream>>>(hpre, sums);
    bn_final_k<<<1, HH, 0, stream>>>(sums, gam + (size_t)l * HH, bet + (size_t)l * HH, sc);
    norm_relu_k<<<(NN * HH + 255) / 256, 256, 0, stream>>>(hpre, sc, h);
  }
  out_proj_k<<<NN / 4, 256, 0, stream>>>(h, oW, ob, out);
}

// Round 2
// 208.915 us; speedup vs baseline: 1.9777x; 1.9777x over previous
//
#include <hip/hip_runtime.h>

#define NN 8000
#define NPAD 8064
#define NE 64000
#define INF 16
#define HH 128
#define MM 16
#define EDF 4
#define OUTF 4
#define NL 2
#define BN_EPS 1e-5f

typedef __attribute__((ext_vector_type(8))) short short8;
typedef __attribute__((ext_vector_type(4))) float f32x4;

static __device__ __forceinline__ unsigned short f2bf(float f) {
  unsigned u = __builtin_bit_cast(unsigned, f);
  u = (u + 0x7fffu + ((u >> 16) & 1u)) >> 16;
  return (unsigned short)u;
}
static __device__ __forceinline__ float bf2f(unsigned short s) {
  unsigned u = ((unsigned)s) << 16;
  return __builtin_bit_cast(float, u);
}

__global__ void deg_count_k(const int* __restrict__ ei, float* __restrict__ deg) {
  int e = blockIdx.x * blockDim.x + threadIdx.x;
  if (e < NE) atomicAdd(&deg[ei[NE + e]], 1.0f);
}

__global__ void in_proj_k(const float* __restrict__ x, const float* __restrict__ W,
                          const float* __restrict__ b, float* __restrict__ h,
                          unsigned short* __restrict__ hb) {
  int n = blockIdx.x;
  int t = threadIdx.x;  // 0..127
  __shared__ float sx[INF];
  if (t < INF) sx[t] = x[n * INF + t];
  __syncthreads();
  float acc = b[t];
#pragma unroll
  for (int i = 0; i < INF; ++i) acc = fmaf(sx[i], W[i * HH + t], acc);
  h[n * HH + t] = acc;
  hb[n * HH + t] = f2bf(acc);
}

// Bp[c][h] = bf16(W2[k, h*16+m]) with c = k*16+m ; c in [0,2048), h in [0,128)
__global__ void bp_build_k(const float* __restrict__ W2, unsigned short* __restrict__ Bp) {
  int idx = blockIdx.x * 256 + threadIdx.x;
  if (idx >= HH * MM * HH) return;
  int c = idx >> 7;
  int hdim = idx & 127;
  int k = c >> 4, m = c & 15;
  Bp[idx] = f2bf(W2[k * (HH * MM) + hdim * MM + m]);
}

// Qn[NPAD x 2048] (bf16) = hb[NPAD x 128] @ Bp^T   (Bp is [2048 x 128], rows = B-cols)
__global__ __launch_bounds__(256) void gemm_qn_mfma(const unsigned short* __restrict__ hb,
                                                    const unsigned short* __restrict__ Bp,
                                                    unsigned short* __restrict__ Qn) {
  __shared__ unsigned short sA[16384];  // 32KB: 128 rows x 128 k, swizzled 16B slots
  __shared__ unsigned short sB[16384];  // 32KB
  int tid = threadIdx.x;
  int bm = blockIdx.y, bn = blockIdx.x;

  const float4* gA = (const float4*)(hb + (size_t)bm * 128 * 128);
  const float4* gB = (const float4*)(Bp + (size_t)bn * 128 * 128);
#pragma unroll
  for (int r = 0; r < 8; ++r) {
    int s = r * 256 + tid;
    int d = s ^ ((s >> 4) & 7);
    float4 va = gA[s];
    float4 vb = gB[s];
    *(float4*)&sA[d * 8] = va;
    *(float4*)&sB[d * 8] = vb;
  }
  __syncthreads();

  int wid = tid >> 6, lane = tid & 63;
  int wr = (wid >> 1) * 64;   // wave row offset in tile
  int wc = (wid & 1) * 64;    // wave col offset in tile
  int l15 = lane & 15, l4 = lane >> 4;

  f32x4 acc[4][4] = {};
#pragma unroll
  for (int ks = 0; ks < 4; ++ks) {
    short8 af[4], bfr[4];
    int kb = ks * 4 + l4;
#pragma unroll
    for (int mr = 0; mr < 4; ++mr) {
      int r = wr + mr * 16 + l15;
      af[mr] = *(const short8*)&sA[(r * 16 + (kb ^ (r & 7))) * 8];
    }
#pragma unroll
    for (int nc = 0; nc < 4; ++nc) {
      int r = wc + nc * 16 + l15;
      bfr[nc] = *(const short8*)&sB[(r * 16 + (kb ^ (r & 7))) * 8];
    }
#pragma unroll
    for (int mr = 0; mr < 4; ++mr)
#pragma unroll
      for (int nc = 0; nc < 4; ++nc)
        acc[mr][nc] = __builtin_amdgcn_mfma_f32_16x16x32_bf16(af[mr], bfr[nc], acc[mr][nc], 0, 0, 0);
  }

#pragma unroll
  for (int mr = 0; mr < 4; ++mr) {
    int r0 = bm * 128 + wr + mr * 16 + l4 * 4;
#pragma unroll
    for (int nc = 0; nc < 4; ++nc) {
      int c0 = bn * 128 + wc + nc * 16 + l15;
#pragma unroll
      for (int j = 0; j < 4; ++j)
        Qn[(size_t)(r0 + j) * (HH * MM) + c0] = f2bf(acc[mr][nc][j]);
    }
  }
}

// B2[n,m] = sum_h h[n,h] * b2[h*16+m]
__global__ void b2_term_k(const float* __restrict__ h, const float* __restrict__ b2,
                          float* __restrict__ B2) {
  __shared__ float sb2[HH * MM];
  for (int i = threadIdx.x; i < HH * MM; i += 256) sb2[i] = b2[i];
  __syncthreads();
  int t = threadIdx.x;
  int n = blockIdx.x * 16 + (t >> 4);
  int m = t & 15;
  const float* hr = h + n * HH;
  float s = 0.f;
#pragma unroll
  for (int k = 0; k < HH; ++k) s = fmaf(hr[k], sb2[k * MM + m], s);
  B2[n * MM + m] = s;
}

// lane = kg*4 + mg (kg 0..15, mg 0..3); 8 edges per wave
__global__ __launch_bounds__(256) void edge_msg_k(const int* __restrict__ ei,
                                                  const float* __restrict__ ea,
                                                  const float* __restrict__ W1,
                                                  const float* __restrict__ b1,
                                                  const unsigned short* __restrict__ Qn,
                                                  const float* __restrict__ B2,
                                                  float* __restrict__ agg) {
  __shared__ float sW1[EDF * HH];
  __shared__ float sb1[HH];
  int tid = threadIdx.x;
  for (int i = tid; i < EDF * HH; i += 256) sW1[i] = W1[i];
  if (tid < HH) sb1[tid] = b1[tid];
  __syncthreads();
  int wid = tid >> 6, lane = tid & 63;
  int kg = lane >> 2, mg = lane & 3;
  int e0 = (blockIdx.x * 4 + wid) * 8;
  for (int t = 0; t < 8; ++t) {
    int e = e0 + t;
    int src = ei[e], dst = ei[NE + e];
    float a0 = ea[e * 4 + 0], a1 = ea[e * 4 + 1], a2 = ea[e * 4 + 2], a3 = ea[e * 4 + 3];
    const unsigned short* q = Qn + (size_t)src * (HH * MM);
    float acc0 = 0.f, acc1 = 0.f, acc2 = 0.f, acc3 = 0.f;
#pragma unroll
    for (int j = 0; j < 8; ++j) {
      int k = j * 16 + kg;
      float r = fmaf(a3, sW1[3 * HH + k],
                 fmaf(a2, sW1[2 * HH + k], fmaf(a1, sW1[HH + k], fmaf(a0, sW1[k], sb1[k]))));
      r = fmaxf(r, 0.f);
      ushort4 qv = *(const ushort4*)&q[k * MM + mg * 4];
      acc0 = fmaf(r, bf2f(qv.x), acc0);
      acc1 = fmaf(r, bf2f(qv.y), acc1);
      acc2 = fmaf(r, bf2f(qv.z), acc2);
      acc3 = fmaf(r, bf2f(qv.w), acc3);
    }
#pragma unroll
    for (int msk = 4; msk <= 32; msk <<= 1) {
      acc0 += __shfl_xor(acc0, msk);
      acc1 += __shfl_xor(acc1, msk);
      acc2 += __shfl_xor(acc2, msk);
      acc3 += __shfl_xor(acc3, msk);
    }
    if (kg == 0) {
      int m0 = mg * 4;
      const float* b2r = B2 + (size_t)src * MM + m0;
      float* ar = agg + (size_t)dst * MM + m0;
      atomicAdd(ar + 0, acc0 + b2r[0]);
      atomicAdd(ar + 1, acc1 + b2r[1]);
      atomicAdd(ar + 2, acc2 + b2r[2]);
      atomicAdd(ar + 3, acc3 + b2r[3]);
    }
  }
}

// x_msg = agg/deg + h@rootW + cbias ; h_pre = h + x_msg@msgW + msgb
__global__ void node_update_k(const float* __restrict__ h, const float* __restrict__ agg,
                              const float* __restrict__ deg, const float* __restrict__ rootW,
                              const float* __restrict__ cbias, const float* __restrict__ msgW,
                              const float* __restrict__ msgb, float* __restrict__ h_pre) {
  int n = blockIdx.x;
  int t = threadIdx.x;  // 0..127
  __shared__ float sh[HH];
  __shared__ float xm[MM];
  sh[t] = h[n * HH + t];
  __syncthreads();
  if (t < MM) {
    float s = 0.f;
#pragma unroll
    for (int k = 0; k < HH; ++k) s = fmaf(sh[k], rootW[k * MM + t], s);
    xm[t] = agg[n * MM + t] / fmaxf(deg[n], 1.0f) + s + cbias[t];
  }
  __syncthreads();
  float hp = sh[t] + msgb[t];
#pragma unroll
  for (int m = 0; m < MM; ++m) hp = fmaf(xm[m], msgW[m * HH + t], hp);
  h_pre[n * HH + t] = hp;
}

__global__ void bn_partial_k(const float* __restrict__ hp, float* __restrict__ sums) {
  int c = threadIdx.x;  // 0..127
  int n0 = blockIdx.x * 32;
  float s = 0.f, ss = 0.f;
  for (int i = 0; i < 32; ++i) {
    float v = hp[(n0 + i) * HH + c];
    s += v;
    ss = fmaf(v, v, ss);
  }
  atomicAdd(&sums[c], s);
  atomicAdd(&sums[HH + c], ss);
}

// fused bn_final + normalize + relu ; emits f32 h and bf16 hb
__global__ void norm_relu_k(const float* __restrict__ hp, const float* __restrict__ sums,
                            const float* __restrict__ gamma, const float* __restrict__ beta,
                            float* __restrict__ h, unsigned short* __restrict__ hb) {
  int i4 = blockIdx.x * 256 + threadIdx.x;
  if (i4 >= NN * HH / 4) return;
  int c0 = (i4 * 4) & 127;
  float4 v = ((const float4*)hp)[i4];
  float4 o;
  ushort4 ob;
  float inv = 1.0f / NN;
#pragma unroll
  for (int j = 0; j < 4; ++j) {
    int c = c0 + j;
    float mu = sums[c] * inv;
    float var = sums[HH + c] * inv - mu * mu;
    float s = gamma[c] * rsqrtf(var + BN_EPS);
    float val = (&v.x)[j];
    val = fmaxf(0.f, (val - mu) * s + beta[c]);
    (&o.x)[j] = val;
    (&ob.x)[j] = f2bf(val);
  }
  ((float4*)h)[i4] = o;
  ((ushort4*)hb)[i4] = ob;
}

__global__ void out_proj_k(const float* __restrict__ h, const float* __restrict__ W,
                           const float* __restrict__ b, float* __restrict__ out) {
  int n = blockIdx.x * 4 + (threadIdx.x >> 6);
  int lane = threadIdx.x & 63;
  if (n >= NN) return;
  float acc0 = 0.f, acc1 = 0.f, acc2 = 0.f, acc3 = 0.f;
#pragma unroll
  for (int rep = 0; rep < 2; ++rep) {
    int hh = lane + rep * 64;
    float hv = h[n * HH + hh];
    acc0 = fmaf(hv, W[hh * OUTF + 0], acc0);
    acc1 = fmaf(hv, W[hh * OUTF + 1], acc1);
    acc2 = fmaf(hv, W[hh * OUTF + 2], acc2);
    acc3 = fmaf(hv, W[hh * OUTF + 3], acc3);
  }
#pragma unroll
  for (int s = 32; s > 0; s >>= 1) {
    acc0 += __shfl_down(acc0, s);
    acc1 += __shfl_down(acc1, s);
    acc2 += __shfl_down(acc2, s);
    acc3 += __shfl_down(acc3, s);
  }
  if (lane == 0) {
    out[n * OUTF + 0] = acc0 + b[0];
    out[n * OUTF + 1] = acc1 + b[1];
    out[n * OUTF + 2] = acc2 + b[2];
    out[n * OUTF + 3] = acc3 + b[3];
  }
}

extern "C" void kernel_launch(void* const* d_in, const int* in_sizes, int n_in,
                              void* d_out, int out_size, void* d_ws, size_t ws_size,
                              hipStream_t stream) {
  (void)in_sizes; (void)n_in; (void)out_size; (void)ws_size;
  const float* x    = (const float*)d_in[0];
  const int* ei     = (const int*)d_in[1];
  const float* ea   = (const float*)d_in[2];
  const float* inW  = (const float*)d_in[3];
  const float* inb  = (const float*)d_in[4];
  const float* cW1  = (const float*)d_in[5];
  const float* cb1  = (const float*)d_in[6];
  const float* cW2  = (const float*)d_in[7];
  const float* cb2  = (const float*)d_in[8];
  const float* rW   = (const float*)d_in[9];
  const float* cbias= (const float*)d_in[10];
  const float* gam  = (const float*)d_in[11];
  const float* bet  = (const float*)d_in[12];
  const float* mW   = (const float*)d_in[13];
  const float* mb   = (const float*)d_in[14];
  const float* oW   = (const float*)d_in[15];
  const float* ob   = (const float*)d_in[16];
  float* out = (float*)d_out;

  float* ws = (float*)d_ws;
  size_t off = 0;
  float* deg  = ws + off; off += 8192;
  float* h    = ws + off; off += (size_t)NPAD * HH;
  float* hpre = ws + off; off += (size_t)NPAD * HH;
  float* agg  = ws + off; off += (size_t)NN * MM;
  float* B2   = ws + off; off += (size_t)NN * MM;
  float* sums = ws + off; off += 256;
  unsigned short* Bp = (unsigned short*)(ws + off); off += (size_t)HH * MM * HH / 2;
  unsigned short* hb = (unsigned short*)(ws + off); off += (size_t)NPAD * HH / 2;
  unsigned short* Qn = (unsigned short*)(ws + off); off += (size_t)NPAD * HH * MM / 2;

  hipMemsetAsync(deg, 0, NN * sizeof(float), stream);
  hipMemsetAsync(hb + (size_t)NN * HH, 0, (size_t)(NPAD - NN) * HH * sizeof(unsigned short), stream);
  deg_count_k<<<(NE + 255) / 256, 256, 0, stream>>>(ei, deg);
  in_proj_k<<<NN, HH, 0, stream>>>(x, inW, inb, h, hb);

  for (int l = 0; l < NL; ++l) {
    bp_build_k<<<(HH * MM * HH + 255) / 256, 256, 0, stream>>>(cW2 + (size_t)l * HH * HH * MM, Bp);
    dim3 gg(HH * MM / 128, NPAD / 128);
    gemm_qn_mfma<<<gg, 256, 0, stream>>>(hb, Bp, Qn);
    b2_term_k<<<NN / 16, 256, 0, stream>>>(h, cb2 + (size_t)l * HH * MM, B2);
    hipMemsetAsync(agg, 0, (size_t)NN * MM * sizeof(float), stream);
    edge_msg_k<<<NE / 32, 256, 0, stream>>>(ei, ea, cW1 + (size_t)l * EDF * HH,
                                            cb1 + (size_t)l * HH, Qn, B2, agg);
    node_update_k<<<NN, HH, 0, stream>>>(h, agg, deg, rW + (size_t)l * HH * MM,
                                         cbias + (size_t)l * MM, mW + (size_t)l * MM * HH,
                                         mb + (size_t)l * HH, hpre);
    hipMemsetAsync(sums, 0, 2 * HH * sizeof(float), stream);
    bn_partial_k<<<NN / 32, HH, 0, stream>>>(hpre, sums);
    norm_relu_k<<<(NN * HH / 4 + 255) / 256, 256, 0, stream>>>(hpre, sums, gam + (size_t)l * HH,
                                                               bet + (size_t)l * HH, h, hb);
  }
  out_proj_k<<<NN / 4, 256, 0, stream>>>(h, oW, ob, out);
}